// Round 5
// baseline (389.866 us; speedup 1.0000x reference)
//
#include <hip/hip_runtime.h>

#define SEGS 100
#define SEGP 101          // padded stride, coprime with 32 banks
#define NREP 8            // accumulator replicas per channel (lane & 7)
#define C_TILE 4
#define BLOCK 1024

typedef float vfloat4 __attribute__((ext_vector_type(4)));

// order-preserving float->uint encoding (monotone: a<b <=> enc(a)<enc(b))
__device__ __forceinline__ unsigned enc_f32(float f) {
    unsigned u = __float_as_uint(f);
    return u ^ (unsigned)(((int)u >> 31) | 0x80000000);
}
__device__ __forceinline__ float dec_f32(unsigned u) {
    unsigned m = (u & 0x80000000u) ? 0x80000000u : 0xFFFFFFFFu;
    return __uint_as_float(u ^ m);
}

// ---------------- main kernel: unroll-8, SGPR-uniform bases ----------------
__global__ __launch_bounds__(BLOCK) void seg_max_v5(
    const float* __restrict__ pf,    // (B, C, N)
    const int* __restrict__ labels,  // (B, N) int32
    float* __restrict__ out,         // (B*SEGS, C)
    int C, int N)
{
    __shared__ unsigned acc[C_TILE * NREP * SEGP];  // 12.9 KB

    const int tid = threadIdx.x;
    const int tiles_per_b = C / C_TILE;             // 32
    const int b = blockIdx.x / tiles_per_b;
    const int c_base = (blockIdx.x % tiles_per_b) * C_TILE;

    for (int i = tid; i < C_TILE * NREP * SEGP; i += BLOCK) acc[i] = 0x007FFFFFu;
    __syncthreads();

    const int wave  = tid >> 6;
    const int lane  = tid & 63;
    // wave-uniform scalars -> force into SGPRs (lane-invariant, safe)
    const int cl    = __builtin_amdgcn_readfirstlane(wave & (C_TILE - 1));
    const int strip = __builtin_amdgcn_readfirstlane(wave >> 2);
    const int c     = __builtin_amdgcn_readfirstlane(c_base + cl);
    const int rep   = lane & (NREP - 1);

    const vfloat4* pf4  = (const vfloat4*)(pf + ((size_t)b * C + c) * (size_t)N);
    const int4*    lb4  = (const int4*)(labels + (size_t)b * N);
    unsigned*      accc = acc + (cl * NREP + rep) * SEGP;

    const int iters = N / 4 / 256;           // 64

    #pragma unroll 8
    for (int it = 0; it < iters; ++it) {
        int idx4 = it * 256 + strip * 64 + lane;
        vfloat4 f = __builtin_nontemporal_load(&pf4[idx4]);
        int4 l4   = lb4[idx4];
        atomicMax(&accc[l4.x], enc_f32(f.x));
        atomicMax(&accc[l4.y], enc_f32(f.y));
        atomicMax(&accc[l4.z], enc_f32(f.z));
        atomicMax(&accc[l4.w], enc_f32(f.w));
    }

    __syncthreads();
    if (tid < C_TILE * SEGS) {
        int ocl = tid & (C_TILE - 1);
        int l   = tid >> 2;
        unsigned m = 0x007FFFFFu;
        #pragma unroll
        for (int r = 0; r < NREP; ++r) {
            unsigned v = acc[(ocl * NREP + r) * SEGP + l];
            m = v > m ? v : m;
        }
        out[((size_t)(b * SEGS + l)) * C + c_base + ocl] = dec_f32(m);
    }
}

// ---------------- probe: verbatim R4 kernel, output to scratch ----------------
// Appended purely to measure main-kernel duration: dur(R5) - dur(R4) = main_v5
__global__ __launch_bounds__(BLOCK) void seg_max_probe(
    const float* __restrict__ pf,
    const int* __restrict__ labels,
    float* __restrict__ out,
    int C, int N)
{
    __shared__ unsigned acc[C_TILE * NREP * SEGP];

    const int tid = threadIdx.x;
    const int tiles_per_b = C / C_TILE;
    const int b = blockIdx.x / tiles_per_b;
    const int c_base = (blockIdx.x % tiles_per_b) * C_TILE;

    for (int i = tid; i < C_TILE * NREP * SEGP; i += BLOCK) acc[i] = 0x007FFFFFu;
    __syncthreads();

    const int wave  = tid >> 6;
    const int lane  = tid & 63;
    const int cl    = wave & (C_TILE - 1);
    const int strip = wave >> 2;
    const int c     = c_base + cl;
    const int rep   = lane & (NREP - 1);

    const vfloat4* pf4  = (const vfloat4*)(pf + ((size_t)b * C + c) * (size_t)N);
    const int4*    lb4  = (const int4*)(labels + (size_t)b * N);
    unsigned*      accc = acc + (cl * NREP + rep) * SEGP;

    const int iters = N / 4 / 256;

    #pragma unroll 4
    for (int it = 0; it < iters; ++it) {
        int idx4 = it * 256 + strip * 64 + lane;
        vfloat4 f = __builtin_nontemporal_load(&pf4[idx4]);
        int4 l4   = lb4[idx4];
        atomicMax(&accc[l4.x], enc_f32(f.x));
        atomicMax(&accc[l4.y], enc_f32(f.y));
        atomicMax(&accc[l4.z], enc_f32(f.z));
        atomicMax(&accc[l4.w], enc_f32(f.w));
    }

    __syncthreads();
    if (tid < C_TILE * SEGS) {
        int ocl = tid & (C_TILE - 1);
        int l   = tid >> 2;
        unsigned m = 0x007FFFFFu;
        #pragma unroll
        for (int r = 0; r < NREP; ++r) {
            unsigned v = acc[(ocl * NREP + r) * SEGP + l];
            m = v > m ? v : m;
        }
        out[((size_t)(b * SEGS + l)) * C + c_base + ocl] = dec_f32(m);
    }
}

extern "C" void kernel_launch(void* const* d_in, const int* in_sizes, int n_in,
                              void* d_out, int out_size, void* d_ws, size_t ws_size,
                              hipStream_t stream) {
    const float* pf  = (const float*)d_in[0];   // (B, C, N) fp32
    const int*   lab = (const int*)d_in[2];     // (B, N) int32
    float*       out = (float*)d_out;           // (B*SEGS, C) fp32

    const long long bn = in_sizes[2];           // B*N
    const int C = (int)(in_sizes[0] / bn);      // 128
    const int B = out_size / (SEGS * C);        // 8
    const int N = (int)(bn / B);                // 65536

    const int blocks = B * (C / C_TILE);        // 256
    seg_max_v5<<<blocks, BLOCK, 0, stream>>>(pf, lab, out, C, N);
    // timing probe (R4-identical cost), writes to scratch only
    seg_max_probe<<<blocks, BLOCK, 0, stream>>>(pf, lab, (float*)d_ws, C, N);
}

// Round 6
// 345.801 us; speedup vs baseline: 1.1274x; 1.1274x over previous
//
#include <hip/hip_runtime.h>

#define SEGS 100
#define SEGP 101          // padded stride, coprime with 32 banks
#define NREP 8            // accumulator replicas per channel (lane & 7)
#define C_TILE 2          // 2 channels/block -> 512 blocks -> 2 blocks/CU
#define BLOCK 1024

typedef float vfloat4 __attribute__((ext_vector_type(4)));

// order-preserving float->uint encoding (monotone: a<b <=> enc(a)<enc(b))
__device__ __forceinline__ unsigned enc_f32(float f) {
    unsigned u = __float_as_uint(f);
    return u ^ (unsigned)(((int)u >> 31) | 0x80000000);
}
__device__ __forceinline__ float dec_f32(unsigned u) {
    unsigned m = (u & 0x80000000u) ? 0x80000000u : 0xFFFFFFFFu;
    return __uint_as_float(u ^ m);
}

// 2 blocks/CU (32 waves/CU) for BW latency hiding; VGPR capped at 64 by
// __launch_bounds__(1024, 8): 8 waves/SIMD min -> both 16-wave blocks resident.
__global__ __launch_bounds__(BLOCK, 8) void seg_max_v6(
    const float* __restrict__ pf,    // (B, C, N)
    const int* __restrict__ labels,  // (B, N) int32
    float* __restrict__ out,         // (B*SEGS, C)
    int C, int N)
{
    __shared__ unsigned acc[C_TILE * NREP * SEGP];  // 6.5 KB

    const int tid = threadIdx.x;
    const int tiles_per_b = C / C_TILE;             // 64
    const int b = blockIdx.x / tiles_per_b;
    const int c_base = (blockIdx.x % tiles_per_b) * C_TILE;

    for (int i = tid; i < C_TILE * NREP * SEGP; i += BLOCK) acc[i] = 0x007FFFFFu;
    __syncthreads();

    const int wave  = tid >> 6;
    const int lane  = tid & 63;
    // wave-uniform scalars -> SGPRs
    const int cl    = __builtin_amdgcn_readfirstlane(wave & (C_TILE - 1));
    const int strip = __builtin_amdgcn_readfirstlane(wave >> 1);   // 0..7
    const int c     = __builtin_amdgcn_readfirstlane(c_base + cl);
    const int rep   = lane & (NREP - 1);

    const vfloat4* pf4  = (const vfloat4*)(pf + ((size_t)b * C + c) * (size_t)N);
    const int4*    lb4  = (const int4*)(labels + (size_t)b * N);
    unsigned*      accc = acc + (cl * NREP + rep) * SEGP;

    const int iters = N / 4 / 512;           // 32: float4 groups per (strip,lane)

    #pragma unroll 4
    for (int it = 0; it < iters; ++it) {
        int idx4 = it * 512 + strip * 64 + lane;
        vfloat4 f = __builtin_nontemporal_load(&pf4[idx4]);  // streamed, skip L2
        int4 l4   = lb4[idx4];                               // L2-hot shared stream
        atomicMax(&accc[l4.x], enc_f32(f.x));
        atomicMax(&accc[l4.y], enc_f32(f.y));
        atomicMax(&accc[l4.z], enc_f32(f.z));
        atomicMax(&accc[l4.w], enc_f32(f.w));
    }

    __syncthreads();
    // reduce replicas + write out: 200 cells per block
    if (tid < C_TILE * SEGS) {
        int ocl = tid & (C_TILE - 1);
        int l   = tid >> 1;
        unsigned m = 0x007FFFFFu;
        #pragma unroll
        for (int r = 0; r < NREP; ++r) {
            unsigned v = acc[(ocl * NREP + r) * SEGP + l];
            m = v > m ? v : m;
        }
        out[((size_t)(b * SEGS + l)) * C + c_base + ocl] = dec_f32(m);
    }
}

extern "C" void kernel_launch(void* const* d_in, const int* in_sizes, int n_in,
                              void* d_out, int out_size, void* d_ws, size_t ws_size,
                              hipStream_t stream) {
    const float* pf  = (const float*)d_in[0];   // (B, C, N) fp32
    const int*   lab = (const int*)d_in[2];     // (B, N) int32
    float*       out = (float*)d_out;           // (B*SEGS, C) fp32

    const long long bn = in_sizes[2];           // B*N
    const int C = (int)(in_sizes[0] / bn);      // 128
    const int B = out_size / (SEGS * C);        // 8
    const int N = (int)(bn / B);                // 65536

    const int blocks = B * (C / C_TILE);        // 512
    seg_max_v6<<<blocks, BLOCK, 0, stream>>>(pf, lab, out, C, N);
}